// Round 1
// baseline (242.068 us; speedup 1.0000x reference)
//
#include <hip/hip_runtime.h>
#include <hip/hip_bf16.h>

#define BATCH 128
#define SGRID 32
#define NCELL 1024
#define NTOT  1025
#define FD    128
#define NACT  19
#define NEG_INF_F  (-3.4028234663852886e38f)  // jnp.finfo(float32).min
#define BF16_SAFE_F (3.3e38f)                 // < bf16 max finite (3.3895e38)

typedef unsigned short ushort_t;
typedef unsigned int   uint_t;
typedef short   short8   __attribute__((ext_vector_type(8)));
typedef float   floatx16 __attribute__((ext_vector_type(16)));

__device__ __forceinline__ float elu_fast(float v) {   // bf16-accurate ELU
    return v > 0.f ? v : (__expf(v) - 1.f);
}
__device__ __forceinline__ float bf2f(ushort_t h) {
    union { uint_t u; float f; } v; v.u = ((uint_t)h) << 16; return v.f;
}
__device__ __forceinline__ ushort_t f2bf(float f) {   // round-to-nearest-even
    union { float f; uint_t u; } v; v.f = f;
    uint_t r = v.u + 0x7FFFu + ((v.u >> 16) & 1u);
    return (ushort_t)(r >> 16);
}
__device__ __forceinline__ uint_t pkbf(float a, float b) {  // v_cvt_pk_bf16_f32
    union { __hip_bfloat162 h; uint_t u; } v;
    v.h = __float22bfloat162_rn(make_float2(a, b));
    return v.u;
}
__device__ __forceinline__ void unpack2(uint_t u, float& a, float& b) {
    union { uint_t x; float f; } lo, hi;
    lo.x = u << 16; hi.x = u & 0xFFFF0000u;
    a = lo.f; b = hi.f;
}
__device__ __forceinline__ void unpack8(uint4 v, float* f) {
    unpack2(v.x, f[0], f[1]); unpack2(v.y, f[2], f[3]);
    unpack2(v.z, f[4], f[5]); unpack2(v.w, f[6], f[7]);
}
__device__ __forceinline__ void unpack4(uint2 v, float* f) {
    unpack2(v.x, f[0], f[1]); unpack2(v.y, f[2], f[3]);
}

// Swizzled LDS addressing: cell stride 256B (no pad), XOR 16B-granule swizzle
// within the 256B row. Rows advance bank-sets like the old +8-pad stride did
// (4 lanes/bank-set on the MFMA b128 reads) but the tile fits 32 KB exactly.
__device__ __forceinline__ ushort_t* ldsp(ushort_t* base, int cell, int kbyte) {
    return (ushort_t*)((char*)base + cell * 256 + (kbyte ^ ((cell & 15) << 4)));
}
__device__ __forceinline__ const ushort_t* ldsp(const ushort_t* base, int cell, int kbyte) {
    return (const ushort_t*)((const char*)base + cell * 256 + (kbyte ^ ((cell & 15) << 4)));
}

// ---------------------------------------------------------------------------
// Pack GNN weights into MFMA B-fragment order for v_mfma_f32_32x32x16_bf16:
// B[k][n], lane layout n = lane&31, k = (lane>>5)*8 + j (j=0..7).
// group g = ((layer*2 + phase)*4 + ntile)*8*64 + ks*64 + lane; 8 bf16/group.
// ---------------------------------------------------------------------------
__global__ __launch_bounds__(256) void gnn_setup_frags(
    const ushort_t* __restrict__ Ws,   // 3 x 128 x 128, k-major
    const ushort_t* __restrict__ Wn,
    ushort_t* __restrict__ wfrag)
{
    const int g = blockIdx.x * 256 + threadIdx.x;   // 12288 groups
    if (g >= 3 * 2 * 4 * 8 * 64) return;
    const int lane = g & 63;
    const int ks   = (g >> 6) & 7;
    const int nt   = (g >> 9) & 3;
    const int p    = (g >> 11) & 1;
    const int l    = g >> 12;
    const ushort_t* W = (p ? Wn : Ws) + (size_t)l * FD * FD;
    const int k0  = ks * 16 + (lane >> 5) * 8;
    const int col = nt * 32 + (lane & 31);
    ushort_t v[8];
    #pragma unroll
    for (int j = 0; j < 8; ++j) v[j] = W[(size_t)(k0 + j) * FD + col];
    uint4 u;
    u.x = v[0] | ((uint_t)v[1] << 16); u.y = v[2] | ((uint_t)v[3] << 16);
    u.z = v[4] | ((uint_t)v[5] << 16); u.w = v[6] | ((uint_t)v[7] << 16);
    *(uint4*)(wfrag + (size_t)g * 8) = u;
}

// ---------------------------------------------------------------------------
// GNN layer, 4-row tiles (128 cells) x 512 threads. Halo = 2 rows per 4 main
// rows (was 2 per 2): read traffic 67 -> 50 MB/layer. Grid 1152: i&7 = XCD,
// 9 blocks (8 row-quads + meta) per batch share an XCD L2 across layers.
// LDS = 2 x 32 KB swizzled tiles = 64 KB -> 2 blocks/CU (16 waves/CU).
// ---------------------------------------------------------------------------
__global__ __launch_bounds__(512, 4) void gnn_layer(
    const ushort_t* __restrict__ xprev,
    ushort_t* __restrict__ xnext,
    const ushort_t* __restrict__ wfrag_layer,
    const ushort_t* __restrict__ Ws,           // raw weights (meta block only)
    const ushort_t* __restrict__ Wn,
    const ushort_t* __restrict__ bs,
    int meta_valid, int in_bstride)
{
    const int i = blockIdx.x;
    const int xcd = i & 7;
    const int j = i >> 3;                      // 0..143
    const int b = xcd * 16 + j / 9;
    const int rb = j % 9;
    const int t = threadIdx.x;
    const ushort_t* xb = xprev + (size_t)b * in_bstride;
    ushort_t* yb = xnext + (size_t)b * (NTOT * FD);

    __shared__ alignas(16) ushort_t xt[128 * FD];   // 32 KB: x tile / meta scratch
    __shared__ alignas(16) ushort_t at[128 * FD];   // 32 KB: agg tile / meta scratch

    if (rb == 8) {
        // ---- meta node: reduce 1024 cells, then 1x128 GEMM ----
        float* part = (float*)xt;              // 32 x 128 floats (16 KB)
        float* msum = (float*)at;
        float* xm   = (float*)at + FD;
        const int kc = (t & 15) * 8;
        const int cg = t >> 4;                 // 0..31
        float s[8];
        #pragma unroll
        for (int q = 0; q < 8; ++q) s[q] = 0.f;
        #pragma unroll 4
        for (int n = 0; n < 32; ++n) {
            const int cell = cg * 32 + n;
            float f[8]; unpack8(*(const uint4*)(xb + (size_t)cell * FD + kc), f);
            #pragma unroll
            for (int q = 0; q < 8; ++q) s[q] += f[q];
        }
        #pragma unroll
        for (int q = 0; q < 8; ++q) part[cg * FD + kc + q] = s[q];
        __syncthreads();
        if (t < FD) {
            float a = 0.f;
            #pragma unroll
            for (int gI = 0; gI < 32; ++gI) a += part[gI * FD + t];
            msum[t] = a;
            xm[t] = meta_valid ? bf2f(xb[(size_t)NCELL * FD + t]) : 0.f;
        }
        __syncthreads();
        if (t < FD) {
            float a = bf2f(bs[t]);
            #pragma unroll 4
            for (int kk = 0; kk < FD; ++kk)
                a += xm[kk] * bf2f(Ws[kk * FD + t]) + msum[kk] * bf2f(Wn[kk * FD + t]);
            yb[(size_t)NCELL * FD + t] = f2bf(elu_fast(a));
        }
        return;
    }

    // ---- row-quad block: grid rows r0 .. r0+3 (128 cells) ----
    const int r0 = rb * 4;
    const int c  = t >> 4;               // col 0..31 (constant across jj)
    const int k  = (t & 15) * 8;         // feature element offset
    const int kb = k * 2;                // feature byte offset

    // Phase 0: issue ALL global loads (main tile + 2 halo rows + meta) before
    // the first barrier so the agg phase never waits on fresh misses.
    const ushort_t* src = xb + (size_t)(r0 * SGRID) * FD;
    const uint4 zero4 = make_uint4(0u, 0u, 0u, 0u);
    uint4 mainT[4];
    #pragma unroll
    for (int jj = 0; jj < 4; ++jj)
        mainT[jj] = *(const uint4*)(src + (size_t)(jj * SGRID + c) * FD + k);
    const uint4 haloTop = (r0 > 0)
        ? *(const uint4*)(xb + (size_t)((r0 - 1) * SGRID + c) * FD + k) : zero4;
    const uint4 haloBot = (r0 + 4 < SGRID)
        ? *(const uint4*)(xb + (size_t)((r0 + 4) * SGRID + c) * FD + k) : zero4;
    const uint4 metaT = meta_valid
        ? *(const uint4*)(xb + (size_t)NCELL * FD + k) : zero4;

    #pragma unroll
    for (int jj = 0; jj < 4; ++jj)
        *(uint4*)ldsp(xt, jj * SGRID + c, kb) = mainT[jj];
    __syncthreads();

    // Build agg tile (bf16): laterals + inner verticals from LDS; boundary
    // verticals + meta from prefetched registers. jj == tile row.
    #pragma unroll
    for (int jj = 0; jj < 4; ++jj) {
        const int cc = jj * SGRID + c;
        float s[8];
        unpack8(metaT, s);                               // meta contribution
        if (jj == 0) { float f[8]; unpack8(haloTop, f);
            #pragma unroll
            for (int q = 0; q < 8; ++q) s[q] += f[q];
        } else { float f[8]; unpack8(*(const uint4*)ldsp(xt, cc - 32, kb), f);
            #pragma unroll
            for (int q = 0; q < 8; ++q) s[q] += f[q];
        }
        if (jj == 3) { float f[8]; unpack8(haloBot, f);
            #pragma unroll
            for (int q = 0; q < 8; ++q) s[q] += f[q];
        } else { float f[8]; unpack8(*(const uint4*)ldsp(xt, cc + 32, kb), f);
            #pragma unroll
            for (int q = 0; q < 8; ++q) s[q] += f[q];
        }
        if (c > 0) { float f[8]; unpack8(*(const uint4*)ldsp(xt, cc - 1, kb), f);
            #pragma unroll
            for (int q = 0; q < 8; ++q) s[q] += f[q];
        }
        if (c < 31) { float f[8]; unpack8(*(const uint4*)ldsp(xt, cc + 1, kb), f);
            #pragma unroll
            for (int q = 0; q < 8; ++q) s[q] += f[q];
        }
        uint4 u;
        u.x = pkbf(s[0], s[1]); u.y = pkbf(s[2], s[3]);
        u.z = pkbf(s[4], s[5]); u.w = pkbf(s[6], s[7]);
        *(uint4*)ldsp(at, cc, kb) = u;
    }
    __syncthreads();

    // MFMA GEMM: M=128 (2 m-waves x 2 m-tiles) x N=128 (4 n-waves) x K=256.
    const int w  = t >> 6;               // wave 0..7
    const int l  = t & 63;
    const int nw = w & 3;                // n-tile
    const int mw = w >> 2;               // m half (rows mw*64 ..)
    const int m0 = l & 31;
    const int kHi = (l >> 5) * 16;       // byte offset within 32B k-slice

    floatx16 acc0, acc1;
    #pragma unroll
    for (int q = 0; q < 16; ++q) { acc0[q] = 0.f; acc1[q] = 0.f; }

    #pragma unroll
    for (int p = 0; p < 2; ++p) {
        const ushort_t* X = p ? at : xt;
        const ushort_t* WF = wfrag_layer + (size_t)((p * 4 + nw) * 8) * 64 * 8;
        #pragma unroll
        for (int ks = 0; ks < 8; ++ks) {
            const short8 bfrag = *(const short8*)(WF + (size_t)(ks * 64 + l) * 8);
            const int kbyte = ks * 32 + kHi;
            const short8 av0 = *(const short8*)ldsp(X, mw * 64 + m0, kbyte);
            const short8 av1 = *(const short8*)ldsp(X, mw * 64 + 32 + m0, kbyte);
            acc0 = __builtin_amdgcn_mfma_f32_32x32x16_bf16(av0, bfrag, acc0, 0, 0, 0);
            acc1 = __builtin_amdgcn_mfma_f32_32x32x16_bf16(av1, bfrag, acc1, 0, 0, 0);
        }
    }
    __syncthreads();   // all waves done reading xt -> safe to reuse as out tile

    // Epilogue: bias + fast elu -> LDS (bf16, swizzled) -> coalesced stores.
    // C/D map: col=lane&31, row=(reg&3)+8*(reg>>2)+4*(lane>>5).
    const int col = nw * 32 + (l & 31);
    const float bias = bf2f(bs[col]);
    #pragma unroll
    for (int mt = 0; mt < 2; ++mt) {
        const floatx16 A = mt ? acc1 : acc0;
        #pragma unroll
        for (int r = 0; r < 16; ++r) {
            const int rowC = (r & 3) + 8 * (r >> 2) + 4 * (l >> 5);
            const int cell = mw * 64 + mt * 32 + rowC;
            *(ushort_t*)((char*)xt + cell * 256 + ((col * 2) ^ ((cell & 15) << 4)))
                = f2bf(elu_fast(A[r] + bias));
        }
    }
    __syncthreads();
    ushort_t* dst = yb + (size_t)(r0 * SGRID) * FD;
    #pragma unroll
    for (int jj = 0; jj < 4; ++jj) {
        const int cc = jj * SGRID + c;
        *(uint4*)(dst + (size_t)cc * FD + k) = *(const uint4*)ldsp(xt, cc, kb);
    }
}

// ---------------------------------------------------------------------------
// Head: gather + 6-layer MLP + mask. 128 blocks (XCD-swizzled, 1 batch each)
// x 1024 threads = 16 waves doing a 16-way K-split; partials reduced via
// part[16][512] in LDS. LDS ~39 KB.
// ---------------------------------------------------------------------------
__global__ __launch_bounds__(1024) void head_kernel(
    const ushort_t* __restrict__ x,       // bf16, B x 1025 x 128
    const int* __restrict__ pos,
    const int* __restrict__ amask,
    const ushort_t* __restrict__ Wd1, const ushort_t* __restrict__ bd1,
    const ushort_t* __restrict__ Wd2, const ushort_t* __restrict__ bd2,
    const ushort_t* __restrict__ Wd3, const ushort_t* __restrict__ bd3,
    const ushort_t* __restrict__ Wp1, const ushort_t* __restrict__ bp1,
    const ushort_t* __restrict__ Wp2, const ushort_t* __restrict__ bp2,
    const ushort_t* __restrict__ Wp3, const ushort_t* __restrict__ bp3,
    ushort_t* __restrict__ out)           // bf16, B x 19
{
    const int t = threadIdx.x;
    const int b = (blockIdx.x & 7) * 16 + (blockIdx.x >> 3);  // batch on its XCD
    const int q = t >> 6;             // K-split sixteenth (wave id, 0..15)
    const int lane = t & 63;

    __shared__ float st[640];
    __shared__ float bufA[512];
    __shared__ float bufB[512];
    __shared__ float part[16][512];

    const int OFFR[5] = {-1, 0, 1, 0, 0};
    const int OFFC[5] = {0, -1, 0, 1, 0};

    // Gather state (reference's j=(pos+off+1)@[32,1] into 34-wide padded map).
    {
        const int pr = pos[b * 2 + 0], pc = pos[b * 2 + 1];
        for (int e = t; e < 640; e += 1024) {
            const int slot = e >> 7, k = e & 127;
            const int jj = (pr + OFFR[slot] + 1) * SGRID + (pc + OFFC[slot] + 1);
            const int qr = jj / (SGRID + 2), qc = jj % (SGRID + 2);
            float v = 0.f;
            if (qr >= 1 && qr <= SGRID && qc >= 1 && qc <= SGRID)
                v = bf2f(x[((size_t)b * NTOT + (qr - 1) * SGRID + (qc - 1)) * FD + k]);
            st[e] = v;
        }
    }
    __syncthreads();

    // ---- L1: 640 -> 512 (K/16 = 40 per wave; lane owns 8 cols) ----
    {
        float acc[8];
        #pragma unroll
        for (int p = 0; p < 8; ++p) acc[p] = 0.f;
        const int c0 = lane * 8;
        const int kb = q * 40;
        #pragma unroll 8
        for (int k = kb; k < kb + 40; ++k) {
            const float s = st[k];
            float f[8]; unpack8(*(const uint4*)(Wd1 + (size_t)k * 512 + c0), f);
            #pragma unroll
            for (int p = 0; p < 8; ++p) acc[p] += s * f[p];
        }
        #pragma unroll
        for (int p = 0; p < 8; ++p) part[q][c0 + p] = acc[p];
        __syncthreads();
        if (t < 512) {
            float a = bf2f(bd1[t]);
            #pragma unroll
            for (int p = 0; p < 16; ++p) a += part[p][t];
            bufA[t] = elu_fast(a);
        }
        __syncthreads();
    }
    // ---- L2: 512 -> 512 (K/16 = 32) ----
    {
        float acc[8];
        #pragma unroll
        for (int p = 0; p < 8; ++p) acc[p] = 0.f;
        const int c0 = lane * 8;
        const int kb = q * 32;
        #pragma unroll 8
        for (int k = kb; k < kb + 32; ++k) {
            const float s = bufA[k];
            float f[8]; unpack8(*(const uint4*)(Wd2 + (size_t)k * 512 + c0), f);
            #pragma unroll
            for (int p = 0; p < 8; ++p) acc[p] += s * f[p];
        }
        #pragma unroll
        for (int p = 0; p < 8; ++p) part[q][c0 + p] = acc[p];
        __syncthreads();
        if (t < 512) {
            float a = bf2f(bd2[t]);
            #pragma unroll
            for (int p = 0; p < 16; ++p) a += part[p][t];
            bufB[t] = elu_fast(a);
        }
        __syncthreads();
    }
    // ---- L3: 512 -> 256 (K/16 = 32; out -> st[0..255]) ----
    {
        float acc[4];
        #pragma unroll
        for (int p = 0; p < 4; ++p) acc[p] = 0.f;
        const int c0 = lane * 4;
        const int kb = q * 32;
        #pragma unroll 8
        for (int k = kb; k < kb + 32; ++k) {
            const float s = bufB[k];
            float f[4]; unpack4(*(const uint2*)(Wd3 + (size_t)k * 256 + c0), f);
            #pragma unroll
            for (int p = 0; p < 4; ++p) acc[p] += s * f[p];
        }
        #pragma unroll
        for (int p = 0; p < 4; ++p) part[q][c0 + p] = acc[p];
        __syncthreads();
        if (t < 256) {
            float a = bf2f(bd3[t]);
            #pragma unroll
            for (int p = 0; p < 16; ++p) a += part[p][t];
            st[t] = elu_fast(a);
        }
        __syncthreads();
    }
    // ---- L4: 256 -> 256 (K/16 = 16; st -> bufA) ----
    {
        float acc[4];
        #pragma unroll
        for (int p = 0; p < 4; ++p) acc[p] = 0.f;
        const int c0 = lane * 4;
        const int kb = q * 16;
        #pragma unroll 8
        for (int k = kb; k < kb + 16; ++k) {
            const float s = st[k];
            float f[4]; unpack4(*(const uint2*)(Wp1 + (size_t)k * 256 + c0), f);
            #pragma unroll
            for (int p = 0; p < 4; ++p) acc[p] += s * f[p];
        }
        #pragma unroll
        for (int p = 0; p < 4; ++p) part[q][c0 + p] = acc[p];
        __syncthreads();
        if (t < 256) {
            float a = bf2f(bp1[t]);
            #pragma unroll
            for (int p = 0; p < 16; ++p) a += part[p][t];
            bufA[t] = elu_fast(a);
        }
        __syncthreads();
    }
    // ---- L5: 256 -> 256 (bufA -> bufB) ----
    {
        float acc[4];
        #pragma unroll
        for (int p = 0; p < 4; ++p) acc[p] = 0.f;
        const int c0 = lane * 4;
        const int kb = q * 16;
        #pragma unroll 8
        for (int k = kb; k < kb + 16; ++k) {
            const float s = bufA[k];
            float f[4]; unpack4(*(const uint2*)(Wp2 + (size_t)k * 256 + c0), f);
            #pragma unroll
            for (int p = 0; p < 4; ++p) acc[p] += s * f[p];
        }
        #pragma unroll
        for (int p = 0; p < 4; ++p) part[q][c0 + p] = acc[p];
        __syncthreads();
        if (t < 256) {
            float a = bf2f(bp2[t]);
            #pragma unroll
            for (int p = 0; p < 16; ++p) a += part[p][t];
            bufB[t] = elu_fast(a);
        }
        __syncthreads();
    }
    // ---- L6: 256 -> 19 + mask, finite-clamped bf16 ----
    {
        float a = 0.f;
        const int kb = q * 16;
        if (lane < NACT) {
            #pragma unroll 8
            for (int k = kb; k < kb + 16; ++k)
                a += bufB[k] * bf2f(Wp3[(size_t)k * NACT + lane]);
            part[q][lane] = a;
        }
        __syncthreads();
        if (t < NACT) {
            float v = bf2f(bp3[t]);
            #pragma unroll
            for (int p = 0; p < 16; ++p) v += part[p][t];
            v += amask[b * NACT + t] ? 0.f : NEG_INF_F;
            v = fminf(fmaxf(v, -BF16_SAFE_F), BF16_SAFE_F);
            out[b * NACT + t] = f2bf(v);
        }
    }
}

extern "C" void kernel_launch(void* const* d_in, const int* in_sizes, int n_in,
                              void* d_out, int out_size, void* d_ws, size_t ws_size,
                              hipStream_t stream) {
    const ushort_t* gmap  = (const ushort_t*)d_in[0];
    const int*      pos   = (const int*)     d_in[1];
    const int*      amask = (const int*)     d_in[2];
    const ushort_t* Ws    = (const ushort_t*)d_in[3];
    const ushort_t* Wn    = (const ushort_t*)d_in[4];
    const ushort_t* bs    = (const ushort_t*)d_in[5];
    const ushort_t* Wd1   = (const ushort_t*)d_in[6];
    const ushort_t* bd1   = (const ushort_t*)d_in[7];
    const ushort_t* Wd2   = (const ushort_t*)d_in[8];
    const ushort_t* bd2   = (const ushort_t*)d_in[9];
    const ushort_t* Wd3   = (const ushort_t*)d_in[10];
    const ushort_t* bd3   = (const ushort_t*)d_in[11];
    const ushort_t* Wp1   = (const ushort_t*)d_in[12];
    const ushort_t* bp1   = (const ushort_t*)d_in[13];
    const ushort_t* Wp2   = (const ushort_t*)d_in[14];
    const ushort_t* bp2   = (const ushort_t*)d_in[15];
    const ushort_t* Wp3   = (const ushort_t*)d_in[16];
    const ushort_t* bp3   = (const ushort_t*)d_in[17];

    // Workspace: 2 bf16 activation buffers (33.6 MB ea) + 192 KB weight frags.
    ushort_t* x1 = (ushort_t*)d_ws;
    ushort_t* x2 = x1 + (size_t)BATCH * NTOT * FD;
    ushort_t* wfrag = x2 + (size_t)BATCH * NTOT * FD;

    gnn_setup_frags<<<48, 256, 0, stream>>>(Ws, Wn, wfrag);

    const int nblk = 9 * BATCH;   // 1152, XCD-swizzled inside the kernel
    gnn_layer<<<nblk, 512, 0, stream>>>(gmap, x1, wfrag,
                                        Ws, Wn, bs, 0, NCELL * FD);
    gnn_layer<<<nblk, 512, 0, stream>>>(x1, x2, wfrag + 32768,
                                        Ws + FD * FD, Wn + FD * FD, bs + FD, 1, NTOT * FD);
    gnn_layer<<<nblk, 512, 0, stream>>>(x2, x1, wfrag + 65536,
                                        Ws + 2 * FD * FD, Wn + 2 * FD * FD, bs + 2 * FD, 1, NTOT * FD);

    head_kernel<<<BATCH, 1024, 0, stream>>>(x1, pos, amask,
                                            Wd1, bd1, Wd2, bd2, Wd3, bd3,
                                            Wp1, bp1, Wp2, bp2, Wp3, bp3,
                                            (ushort_t*)d_out);
}